// Round 1
// 339.797 us; speedup vs baseline: 1.0062x; 1.0062x over previous
//
#include <hip/hip_runtime.h>

#define S_LEN 2048
#define HID   2048
#define NQH   32
#define NKV   8
#define HD    64

#define BM 256
#define BN 128
#define BK 64

typedef __bf16 bf16x8 __attribute__((ext_vector_type(8)));
typedef __bf16 bf16x4 __attribute__((ext_vector_type(4)));
typedef float  f32x4  __attribute__((ext_vector_type(4)));

#define MFMA16(a, b, c) __builtin_amdgcn_mfma_f32_16x16x32_bf16(a, b, c, 0, 0, 0)

__device__ __forceinline__ void async_copy16(const void* g, void* l) {
  __builtin_amdgcn_global_load_lds(
      (const __attribute__((address_space(1))) unsigned int*)g,
      (__attribute__((address_space(3))) unsigned int*)l, 16, 0, 0);
}

// ---------------- fused f32 -> bf16 cast of x + all weights ----------------
__global__ void cast_all_k(const float* __restrict__ x,  const float* __restrict__ wq,
                           const float* __restrict__ wk, const float* __restrict__ wv,
                           const float* __restrict__ wo,
                           __bf16* __restrict__ xb,  __bf16* __restrict__ wqb,
                           __bf16* __restrict__ wkb, __bf16* __restrict__ wvb,
                           __bf16* __restrict__ wob) {
  int bid = blockIdx.x;
  const float* in; __bf16* out; int base;
  if (bid < 8192)       { in = x;  out = xb;  base = bid; }
  else if (bid < 12288) { in = wq; out = wqb; base = bid - 8192; }
  else if (bid < 13312) { in = wk; out = wkb; base = bid - 12288; }
  else if (bid < 14336) { in = wv; out = wvb; base = bid - 13312; }
  else                  { in = wo; out = wob; base = bid - 14336; }
  int i = (base * 256 + threadIdx.x) * 4;
  float4 v = *(const float4*)(in + i);
  bf16x4 o;
  o[0] = (__bf16)v.x; o[1] = (__bf16)v.y; o[2] = (__bf16)v.z; o[3] = (__bf16)v.w;
  *(bf16x4*)(out + i) = o;
}

// ---------------- pipelined GEMM core: acc = A[M,K] * B[N,K]^T ----------------
// BM=256 BN=128 BK=64, 512 threads (8 waves, 4x2), 3-stage LDS (144 KiB),
// depth-2 prefetch, counted s_waitcnt vmcnt(6) (never 0 in steady state),
// ONE raw s_barrier per K-tile, XOR-swizzled LDS (T2), setprio around MFMA (T5).
__device__ __forceinline__ void gemm_pipe(const __bf16* __restrict__ A,
                                          const __bf16* __restrict__ B,
                                          int m0, int n0, int K,
                                          __bf16 (&As)[3][BM][BK],
                                          __bf16 (&Bs)[3][BN][BK],
                                          f32x4 (&acc)[4][4]) {
  const int tid = threadIdx.x, wave = tid >> 6, lane = tid & 63;
  const int l15 = lane & 15, quad = lane >> 4;
  const int wr = wave >> 1, wc = wave & 1;

  // staging: one gload_lds writes 1 KiB = 8 rows x 128 B (linear dest).
  // source column pre-swizzled by (row&7) so a swizzled ds_read recovers it.
  const int srow = lane >> 3;                       // 0..7 within 8-row group
  const int scol = ((lane & 7) ^ srow) * 8;         // swizzled col (elems)
  const __bf16* ga = A + (size_t)(m0 + wave * 32 + srow) * K + scol;
  const __bf16* gb = B + (size_t)(n0 + wave * 16 + srow) * K + scol;

  // ds_read chunk offsets (bytes/2 = elems), chunk = (kk*4+quad) ^ (row&7)
  const int c0 = ((quad)     ^ (l15 & 7)) * 8;
  const int c1 = ((4 + quad) ^ (l15 & 7)) * 8;

  const int NT = K / BK;  // 32

#define STAGE(st, kt) do {                                                        \
    _Pragma("unroll")                                                             \
    for (int i = 0; i < 4; i++)                                                   \
      async_copy16(ga + (kt) + (size_t)(i * 8) * K, &As[st][wave * 32 + i * 8][0]); \
    _Pragma("unroll")                                                             \
    for (int i = 0; i < 2; i++)                                                   \
      async_copy16(gb + (kt) + (size_t)(i * 8) * K, &Bs[st][wave * 16 + i * 8][0]); \
  } while (0)

  STAGE(0, 0);
  STAGE(1, BK);

  int s = 0;
  for (int t = 0; t < NT; t++) {
    // lgkmcnt(0): my previous tile's ds_reads complete before I pass the
    // barrier (next stage overwrites that buffer). vmcnt(6): wait only for
    // tile t's 6 loads; tile t+1's 6 stay in flight across the barrier.
    if (t + 1 < NT) asm volatile("s_waitcnt vmcnt(6) lgkmcnt(0)" ::: "memory");
    else            asm volatile("s_waitcnt vmcnt(0) lgkmcnt(0)" ::: "memory");
    __builtin_amdgcn_s_barrier();
    asm volatile("" ::: "memory");

    if (t + 2 < NT) {
      int s2 = s + 2; if (s2 >= 3) s2 -= 3;
      STAGE(s2, (t + 2) * BK);
    }

    const __bf16* a0 = &As[s][wr * 64][0];
    const __bf16* b0 = &Bs[s][wc * 64][0];
    bf16x8 af[2][4], bfr[2][4];
#pragma unroll
    for (int mt = 0; mt < 4; mt++) {
      af[0][mt] = *(const bf16x8*)(a0 + (mt * 16 + l15) * BK + c0);
      af[1][mt] = *(const bf16x8*)(a0 + (mt * 16 + l15) * BK + c1);
    }
#pragma unroll
    for (int nt = 0; nt < 4; nt++) {
      bfr[0][nt] = *(const bf16x8*)(b0 + (nt * 16 + l15) * BK + c0);
      bfr[1][nt] = *(const bf16x8*)(b0 + (nt * 16 + l15) * BK + c1);
    }

    __builtin_amdgcn_s_setprio(1);
#pragma unroll
    for (int kk = 0; kk < 2; kk++)
#pragma unroll
      for (int mt = 0; mt < 4; mt++)
#pragma unroll
        for (int nt = 0; nt < 4; nt++)
          acc[mt][nt] = MFMA16(af[kk][mt], bfr[kk][nt], acc[mt][nt]);
    __builtin_amdgcn_s_setprio(0);

    s = s + 1; if (s >= 3) s -= 3;
  }
#undef STAGE
}

// fused QKV projection + RoPE(Q,K) + V transpose. grid (16, 24), 512 thr
__global__ __launch_bounds__(512, 2) void gemm_qkv_k(const __bf16* __restrict__ xb,
    const __bf16* __restrict__ wqb, const __bf16* __restrict__ wkb, const __bf16* __restrict__ wvb,
    const float* __restrict__ bq, const float* __restrict__ bk, const float* __restrict__ bv,
    const float* __restrict__ fr,
    __bf16* __restrict__ Qb, __bf16* __restrict__ Kb, __bf16* __restrict__ Vt) {
  __shared__ __align__(16) __bf16 As[3][BM][BK];
  __shared__ __align__(16) __bf16 Bs[3][BN][BK];
  const int by = blockIdx.y;
  const int m0 = blockIdx.x * BM;
  const __bf16* B; const float* bias; int n0;
  int mode;  // 0 = ropeQ, 1 = ropeK, 2 = vtrans
  if (by < 16)      { B = wqb; bias = bq; n0 = by * 128;        mode = 0; }
  else if (by < 20) { B = wkb; bias = bk; n0 = (by - 16) * 128; mode = 1; }
  else              { B = wvb; bias = bv; n0 = (by - 20) * 128; mode = 2; }

  f32x4 acc[4][4] = {};
  gemm_pipe(xb, B, m0, n0, HID, As, Bs, acc);

  const int tid = threadIdx.x, wave = tid >> 6, lane = tid & 63;
  const int l15 = lane & 15, quad = lane >> 4;
  const int wr = wave >> 1, wc = wave & 1;

  if (mode == 2) {
#pragma unroll
    for (int nt = 0; nt < 4; nt++) {
      int col = n0 + wc * 64 + nt * 16 + l15;       // 0..511
      int g = col >> 6, d = col & 63;
      float bv2 = bias[col];
#pragma unroll
      for (int mt = 0; mt < 4; mt++) {
        int row = m0 + wr * 64 + mt * 16 + quad * 4;
        int b = row >> 11, sI = row & 2047;
        bf16x4 o;
#pragma unroll
        for (int r = 0; r < 4; r++) o[r] = (__bf16)(acc[mt][nt][r] + bv2);
        *(bf16x4*)(Vt + (((size_t)(b * NKV + g) * HD + d)) * S_LEN + sI) = o;
      }
    }
  } else {
    const float scale = (mode == 0) ? 0.125f * 1.44269504f : 1.0f;
    const int ldc = (mode == 0) ? HID : 512;
    __bf16* C = (mode == 0) ? Qb : Kb;
    const int dpar = l15 & 1;
#pragma unroll
    for (int nt = 0; nt < 4; nt++) {
      int col = n0 + wc * 64 + nt * 16 + l15;
      int d = col & 63;
      float bv2 = bias[col];
#pragma unroll
      for (int mt = 0; mt < 4; mt++) {
        int row = m0 + wr * 64 + mt * 16 + quad * 4;
        int sI = row & 2047;
#pragma unroll
        for (int r = 0; r < 4; r++) {
          float v = acc[mt][nt][r] + bv2;
          float p = __shfl_xor(v, 1, 64);
          float f = fr[(size_t)(sI + r) * HD + d];
          float fp = __shfl_xor(f, 1, 64);
          float o = dpar ? (p * f + v * fp) : (v * f - p * fp);
          C[(size_t)(row + r) * ldc + col] = (__bf16)(o * scale);
        }
      }
    }
  }
}

// output projection: grid (16, 16), 512 thr
__global__ __launch_bounds__(512, 2) void gemm_out_k(const __bf16* __restrict__ A,
    const __bf16* __restrict__ Bw, const float* __restrict__ bias, float* __restrict__ C) {
  __shared__ __align__(16) __bf16 As[3][BM][BK];
  __shared__ __align__(16) __bf16 Bs[3][BN][BK];
  const int m0 = blockIdx.x * BM, n0 = blockIdx.y * BN;
  f32x4 acc[4][4] = {};
  gemm_pipe(A, Bw, m0, n0, HID, As, Bs, acc);
  const int tid = threadIdx.x, wave = tid >> 6, lane = tid & 63;
  const int l15 = lane & 15, quad = lane >> 4;
  const int wr = wave >> 1, wc = wave & 1;
#pragma unroll
  for (int nt = 0; nt < 4; nt++) {
    int col = n0 + wc * 64 + nt * 16 + l15;
    float bv = bias[col];
#pragma unroll
    for (int mt = 0; mt < 4; mt++) {
      int row = m0 + wr * 64 + mt * 16 + quad * 4;
#pragma unroll
      for (int r = 0; r < 4; r++)
        C[(size_t)(row + r) * HID + col] = acc[mt][nt][r] + bv;
    }
  }
}

// ---------------- Flash attention v6: uniform-work blocks ----------------
// 64-row q-tiles (32 tiles). Block y processes the PAIR (qt=y, qt=31-y):
// kv-iters = (y+1)+(32-y) = 33 for EVERY block -> zero drain tail at 4 blocks/CU.
// 4 waves x 16 q-rows; no-max softmax (exp2, Q pre-scaled log2e/8); rsum via
// ones-MFMA; swizzled LDS, XOR-decomposed addresses.
__global__ __launch_bounds__(256, 4) void flash_k(const __bf16* __restrict__ Q,
                                                  const __bf16* __restrict__ K,
                                                  const __bf16* __restrict__ Vt,
                                                  __bf16* __restrict__ O) {
  __shared__ __align__(64) __bf16 Ksm[64][64];       // [kv][d] swizzled (key=row&7)
  __shared__ __align__(64) __bf16 Vsm[64][64];       // [d][kv] swizzled
  __shared__ __align__(64) __bf16 Psm[4][16][64];    // per-wave [q][kv] swizzled
  const int tid = threadIdx.x;
  const int wave = tid >> 6, lane = tid & 63;
  const int l15 = lane & 15, quad = lane >> 4;
  const int x7 = l15 & 7, l15h = l15 >> 3;
  const int bh = blockIdx.x;
  const int b = bh >> 5, h = bh & 31, g = h >> 2;

  const int srow = tid >> 2, sc = (tid & 3) * 16;
  const int r7 = srow & 7;
  const int w0 = (((sc >> 3))     ^ r7) * 8;
  const int w1 = (((sc >> 3) + 1) ^ r7) * 8;

  char* kbp = (char*)&Ksm[0][0];
  char* vbp = (char*)&Vsm[0][0];
  char* pbp = (char*)&Psm[0][0][0];
  int kr[2], pr[2], pw[4];
#pragma unroll
  for (int ks = 0; ks < 2; ks++) {
    kr[ks] = l15 * 128 + (((ks * 4 + quad) ^ x7) * 16);
    pr[ks] = wave * 2048 + kr[ks];
  }
#pragma unroll
  for (int nt = 0; nt < 4; nt++)
    pw[nt] = wave * 2048 + quad * 512 + x7 * 2 + (((2 * nt + l15h) ^ ((quad & 1) * 4)) * 16);

  bf16x8 ones;
#pragma unroll
  for (int j = 0; j < 8; j++) ones[j] = (__bf16)1.0f;

  const __bf16* kbase = K + ((size_t)b * S_LEN + srow) * (NKV * HD) + g * HD + sc;
  const __bf16* vbase = Vt + (((size_t)b * NKV + g) * HD + srow) * S_LEN + sc;

#pragma unroll 1
  for (int half = 0; half < 2; half++) {
    const int qt = half ? (31 - (int)blockIdx.y) : (int)blockIdx.y;
    const int wq0 = qt * 64 + wave * 16;

    const __bf16* qp = Q + ((size_t)(b * S_LEN + wq0 + l15)) * HID + h * HD + quad * 8;
    bf16x8 qf0 = *(const bf16x8*)qp;
    bf16x8 qf1 = *(const bf16x8*)(qp + 32);

    f32x4 acc[4] = {};
    f32x4 accs = {};

    const __bf16* kp = kbase;
    const __bf16* vp = vbase;
    uint4 k0 = *(const uint4*)kp, k1 = *(const uint4*)(kp + 8);
    uint4 v0 = *(const uint4*)vp, v1 = *(const uint4*)(vp + 8);

    for (int t = 0; t <= qt; t++) {
      const int kv0 = t * 64;
      __syncthreads();
      *(uint4*)&Ksm[srow][w0] = k0;
      *(uint4*)&Ksm[srow][w1] = k1;
      *(uint4*)&Vsm[srow][w0] = v0;
      *(uint4*)&Vsm[srow][w1] = v1;
      if (t < qt) {
        kp += 64 * NKV * HD;  vp += 64;
        k0 = *(const uint4*)kp; k1 = *(const uint4*)(kp + 8);
        v0 = *(const uint4*)vp; v1 = *(const uint4*)(vp + 8);
      }
      __syncthreads();

      if (kv0 > wq0 + 15) continue;   // fully masked for this wave

      bf16x8 kf[2][4];
#pragma unroll
      for (int ks = 0; ks < 2; ks++)
#pragma unroll
        for (int nt = 0; nt < 4; nt++)
          kf[ks][nt] = *(const bf16x8*)(kbp + (kr[ks] + nt * 2048));

      f32x4 sacc[4] = {};
#pragma unroll
      for (int nt = 0; nt < 4; nt++) {
        sacc[nt] = MFMA16(qf0, kf[0][nt], sacc[nt]);
        sacc[nt] = MFMA16(qf1, kf[1][nt], sacc[nt]);
      }
      const bool domask = (kv0 + 63 > wq0);
#pragma unroll
      for (int nt = 0; nt < 4; nt++) {
        int kv = kv0 + nt * 16 + l15;
        int qr = wq0 + quad * 4;
#pragma unroll
        for (int r = 0; r < 4; r++) {
          float p = __builtin_exp2f(sacc[nt][r]);     // Q pre-scaled by log2e/8
          if (domask && kv > qr + r) p = 0.f;
          *(__bf16*)(pbp + ((pw[nt] ^ (r << 4)) + r * 128)) = (__bf16)p;
        }
      }

      // O += P V ; rsum += P * 1
#pragma unroll
      for (int ks = 0; ks < 2; ks++) {
        bf16x8 vf[4];
#pragma unroll
        for (int nt = 0; nt < 4; nt++)
          vf[nt] = *(const bf16x8*)(vbp + (kr[ks] + nt * 2048));
        bf16x8 pf = *(const bf16x8*)(pbp + pr[ks]);
        accs = MFMA16(pf, ones, accs);
#pragma unroll
        for (int nt = 0; nt < 4; nt++)
          acc[nt] = MFMA16(pf, vf[nt], acc[nt]);
      }
    }

    // epilogue: ones-acc rows (quad*4+r) match O-acc rows -> no shuffles
    __bf16* op = O + ((size_t)(b * S_LEN + wq0 + quad * 4)) * HID + h * HD;
    float inv[4];
#pragma unroll
    for (int r = 0; r < 4; r++) inv[r] = 1.f / accs[r];
#pragma unroll
    for (int nt = 0; nt < 4; nt++)
#pragma unroll
      for (int r = 0; r < 4; r++)
        op[(size_t)r * HID + nt * 16 + l15] = (__bf16)(acc[nt][r] * inv[r]);
  }
}

extern "C" void kernel_launch(void* const* d_in, const int* in_sizes, int n_in,
                              void* d_out, int out_size, void* d_ws, size_t ws_size,
                              hipStream_t stream) {
  (void)in_sizes; (void)n_in; (void)out_size; (void)ws_size;
  const float* x  = (const float*)d_in[0];
  const float* fr = (const float*)d_in[1];
  const float* wq = (const float*)d_in[3];
  const float* bq = (const float*)d_in[4];
  const float* wk = (const float*)d_in[5];
  const float* bk = (const float*)d_in[6];
  const float* wv = (const float*)d_in[7];
  const float* bv = (const float*)d_in[8];
  const float* wo = (const float*)d_in[9];
  const float* bo = (const float*)d_in[10];
  float* out = (float*)d_out;
  char* ws = (char*)d_ws;

  __bf16* xb  = (__bf16*)(ws);
  __bf16* wqb = (__bf16*)(ws + ((size_t)16 << 20));
  __bf16* wkb = (__bf16*)(ws + ((size_t)24 << 20));
  __bf16* wvb = (__bf16*)(ws + ((size_t)26 << 20));
  __bf16* wob = (__bf16*)(ws + ((size_t)28 << 20));
  __bf16* Qb  = (__bf16*)(ws + ((size_t)36 << 20));
  __bf16* Kb  = (__bf16*)(ws + ((size_t)52 << 20));
  __bf16* Vtb = (__bf16*)(ws + ((size_t)60 << 20));
  __bf16* Ab  = (__bf16*)(ws + ((size_t)64 << 20));

  cast_all_k<<<18432, 256, 0, stream>>>(x, wq, wk, wv, wo, xb, wqb, wkb, wvb, wob);

  gemm_qkv_k<<<dim3(16, 24), 512, 0, stream>>>(xb, wqb, wkb, wvb, bq, bk, bv, fr, Qb, Kb, Vtb);

  flash_k<<<dim3(64, 16), 256, 0, stream>>>(Qb, Kb, Vtb, Ab);

  gemm_out_k<<<dim3(16, 16), 512, 0, stream>>>(Ab, wob, bo, out);
}